// Round 3
// baseline (247.881 us; speedup 1.0000x reference)
//
#include <hip/hip_runtime.h>

// QCausalConv1D: x[B,D,L] int8 (as int32), weight[D,W=4] int8 (as int32),
// bias[D] int8 (as int32), 4 fp32 scalar scales.
// y[b,d,l] = silu( (sum_{k=0..3} x[b,d,l-3+k]*w[d,k]) * in_s*w_s + bias[d]*b_s )
// out = clip(rint(y/out_s), -128, 127) as int32.
// B=2, D=4096, L=4096 hard-wired (harness shapes are fixed).
//
// R3: same as R2 but with clang native vectors (ext_vector_type) so
// __builtin_nontemporal_store compiles. 8 elems/thread, halo via __shfl_up,
// nontemporal streaming stores.

#define LMASK 4095   // L-1
#define DMASK 4095   // D-1
#define LSHIFT 12    // log2(L)

typedef int iv4 __attribute__((ext_vector_type(4)));

__device__ __forceinline__ int silu_requant(float y, float inv_out) {
    // silu(y) = y / (1 + exp(-y)); rintf = round-half-even matches np.round
    float e = __expf(-y);
    float s = y * __builtin_amdgcn_rcpf(1.0f + e);
    float q = rintf(s * inv_out);
    q = fminf(fmaxf(q, -128.0f), 127.0f);
    return (int)q;
}

__global__ __launch_bounds__(256) void qconv1d_kernel(
    const int* __restrict__ x,
    const int* __restrict__ w,
    const int* __restrict__ bias,
    const float* __restrict__ in_s_p,
    const float* __restrict__ w_s_p,
    const float* __restrict__ out_s_p,
    const float* __restrict__ b_s_p,
    int* __restrict__ out)
{
    const int t   = blockIdx.x * blockDim.x + threadIdx.x; // 8 elems / thread
    const int c0i = t << 1;              // first 16B-chunk index
    const int e   = t << 3;              // global element base (< 2^26)
    const int pos = e & LMASK;           // position within row
    const int d   = (e >> LSHIFT) & DMASK;

    const iv4* __restrict__ xv = (const iv4*)x;
    iv4 c0 = xv[c0i];
    iv4 c1 = xv[c0i + 1];

    // Halo = chunk c0i-1 (we use its last 3 ints). For lanes 1..63 that is
    // lane-1's c1 -> cross-lane shuffle, no memory traffic. Lane 0 loads it
    // (16B per wave). Row starts get zeros (causal pad).
    iv4 h;
    h.x = __shfl_up(c1.x, 1);
    h.y = __shfl_up(c1.y, 1);
    h.z = __shfl_up(c1.z, 1);
    h.w = __shfl_up(c1.w, 1);
    const int lane = threadIdx.x & 63;
    if (lane == 0 && pos != 0) h = xv[c0i - 1];
    if (pos == 0) h = (iv4){0, 0, 0, 0};

    iv4 wv = ((const iv4*)w)[d];

    // int8*int8 dot products <= 4*128*128: exact in fp32 -> full-rate FMA
    const float w0 = (float)wv.x, w1 = (float)wv.y, w2 = (float)wv.z, w3 = (float)wv.w;

    // sequence s[-3..7]
    float sm3 = (float)h.y,  sm2 = (float)h.z,  sm1 = (float)h.w;
    float s0 = (float)c0.x, s1 = (float)c0.y, s2 = (float)c0.z, s3 = (float)c0.w;
    float s4 = (float)c1.x, s5 = (float)c1.y, s6 = (float)c1.z, s7 = (float)c1.w;

    float a0 = w0*sm3 + w1*sm2 + w2*sm1 + w3*s0;
    float a1 = w0*sm2 + w1*sm1 + w2*s0  + w3*s1;
    float a2 = w0*sm1 + w1*s0  + w2*s1  + w3*s2;
    float a3 = w0*s0  + w1*s1  + w2*s2  + w3*s3;
    float a4 = w0*s1  + w1*s2  + w2*s3  + w3*s4;
    float a5 = w0*s2  + w1*s3  + w2*s4  + w3*s5;
    float a6 = w0*s3  + w1*s4  + w2*s5  + w3*s6;
    float a7 = w0*s4  + w1*s5  + w2*s6  + w3*s7;

    const float in_s  = in_s_p[0];
    const float w_s   = w_s_p[0];
    const float out_s = out_s_p[0];
    const float b_s   = b_s_p[0];

    const float s_xw    = in_s * w_s;
    const float inv_out = 1.0f / out_s;
    const float bf      = (float)bias[d] * b_s;

    iv4 q0, q1;
    q0.x = silu_requant(a0 * s_xw + bf, inv_out);
    q0.y = silu_requant(a1 * s_xw + bf, inv_out);
    q0.z = silu_requant(a2 * s_xw + bf, inv_out);
    q0.w = silu_requant(a3 * s_xw + bf, inv_out);
    q1.x = silu_requant(a4 * s_xw + bf, inv_out);
    q1.y = silu_requant(a5 * s_xw + bf, inv_out);
    q1.z = silu_requant(a6 * s_xw + bf, inv_out);
    q1.w = silu_requant(a7 * s_xw + bf, inv_out);

    iv4* ov = (iv4*)out;
    __builtin_nontemporal_store(q0, &ov[c0i]);
    __builtin_nontemporal_store(q1, &ov[c0i + 1]);
}

extern "C" void kernel_launch(void* const* d_in, const int* in_sizes, int n_in,
                              void* d_out, int out_size, void* d_ws, size_t ws_size,
                              hipStream_t stream) {
    const int*   x    = (const int*)d_in[0];
    const int*   w    = (const int*)d_in[1];
    const int*   bias = (const int*)d_in[2];
    const float* is   = (const float*)d_in[3];
    const float* ws   = (const float*)d_in[4];
    const float* os   = (const float*)d_in[5];
    const float* bs   = (const float*)d_in[6];
    int* out = (int*)d_out;

    const int threads = out_size >> 3;         // 4,194,304 (exact)
    const int block   = 256;
    const int grid    = threads / block;       // 16384 (exact)

    qconv1d_kernel<<<grid, block, 0, stream>>>(x, w, bias, is, ws, os, bs, out);
}

// Round 4
// 245.769 us; speedup vs baseline: 1.0086x; 1.0086x over previous
//
#include <hip/hip_runtime.h>

// QCausalConv1D: x[B,D,L] int8 (as int32), weight[D,W=4] int8 (as int32),
// bias[D] int8 (as int32), 4 fp32 scalar scales.
// y[b,d,l] = silu( (sum_{k=0..3} x[b,d,l-3+k]*w[d,k]) * in_s*w_s + bias[d]*b_s )
// out = clip(rint(y/out_s), -128, 127) as int32.
// B=2, D=4096, L=4096 hard-wired (harness shapes are fixed).
//
// R4: 16 elems/thread, 4x dwordx4 loads + 1 halo dwordx4 (L1/L2-hit: same
// lines the neighboring lane loads) + 4 plain dwordx4 stores. No shuffles
// (R3's ds_permute serialized vmcnt->lgkmcnt on the critical path: 85us at
// only 2.5 TB/s / 22% VALU = latency-bound). Weight/bias scalarized via
// readfirstlane (d is wave-uniform: wave = 1024 consecutive elems, row=4096).

#define LMASK 4095   // L-1
#define DMASK 4095   // D-1
#define LSHIFT 12    // log2(L)

typedef int iv4 __attribute__((ext_vector_type(4)));

__device__ __forceinline__ int silu_requant(float y, float inv_out) {
    // silu(y) = y / (1 + exp(-y)); rintf = round-half-even matches np.round
    float e = __expf(-y);
    float s = y * __builtin_amdgcn_rcpf(1.0f + e);
    float q = rintf(s * inv_out);
    q = fminf(fmaxf(q, -128.0f), 127.0f);
    return (int)q;
}

__global__ __launch_bounds__(256) void qconv1d_kernel(
    const int* __restrict__ x,
    const int* __restrict__ w,
    const int* __restrict__ bias,
    const float* __restrict__ in_s_p,
    const float* __restrict__ w_s_p,
    const float* __restrict__ out_s_p,
    const float* __restrict__ b_s_p,
    int* __restrict__ out)
{
    const int t    = blockIdx.x * blockDim.x + threadIdx.x; // 16 elems/thread
    const int base = t << 2;             // first 16B-chunk index (int4 units)
    const int e    = t << 4;             // global element base (< 2^26)
    const int pos  = e & LMASK;          // position within row
    const int d    = (e >> LSHIFT) & DMASK;

    const iv4* __restrict__ xv = (const iv4*)x;

    // 5 independent loads issued back-to-back: 80 B/lane in flight.
    iv4 c0 = xv[base + 0];
    iv4 c1 = xv[base + 1];
    iv4 c2 = xv[base + 2];
    iv4 c3 = xv[base + 3];
    iv4 h  = (iv4){0, 0, 0, 0};
    if (pos != 0) h = xv[base - 1];      // halo: cache-hit (neighbor's lines)

    // d is wave-uniform -> scalar loads for weight/bias.
    const int dw = __builtin_amdgcn_readfirstlane(d);
    iv4 wv = ((const iv4*)w)[dw];
    const float bias_i = (float)bias[dw];

    const float w0 = (float)wv.x, w1 = (float)wv.y, w2 = (float)wv.z, w3 = (float)wv.w;

    // sequence s[0..18] = x[e-3 .. e+15]; int8 dot exact in fp32
    float s[19];
    s[0] = (float)h.y;  s[1] = (float)h.z;  s[2] = (float)h.w;
    s[3]  = (float)c0.x; s[4]  = (float)c0.y; s[5]  = (float)c0.z; s[6]  = (float)c0.w;
    s[7]  = (float)c1.x; s[8]  = (float)c1.y; s[9]  = (float)c1.z; s[10] = (float)c1.w;
    s[11] = (float)c2.x; s[12] = (float)c2.y; s[13] = (float)c2.z; s[14] = (float)c2.w;
    s[15] = (float)c3.x; s[16] = (float)c3.y; s[17] = (float)c3.z; s[18] = (float)c3.w;

    const float in_s  = in_s_p[0];
    const float w_s   = w_s_p[0];
    const float out_s = out_s_p[0];
    const float b_s   = b_s_p[0];

    const float s_xw    = in_s * w_s;
    const float inv_out = 1.0f / out_s;
    const float bf      = bias_i * b_s;

    int q[16];
#pragma unroll
    for (int i = 0; i < 16; ++i) {
        float a = w0 * s[i] + w1 * s[i + 1] + w2 * s[i + 2] + w3 * s[i + 3];
        q[i] = silu_requant(a * s_xw + bf, inv_out);
    }

    iv4* ov = (iv4*)out;
    ov[base + 0] = (iv4){q[0],  q[1],  q[2],  q[3]};
    ov[base + 1] = (iv4){q[4],  q[5],  q[6],  q[7]};
    ov[base + 2] = (iv4){q[8],  q[9],  q[10], q[11]};
    ov[base + 3] = (iv4){q[12], q[13], q[14], q[15]};
}

extern "C" void kernel_launch(void* const* d_in, const int* in_sizes, int n_in,
                              void* d_out, int out_size, void* d_ws, size_t ws_size,
                              hipStream_t stream) {
    const int*   x    = (const int*)d_in[0];
    const int*   w    = (const int*)d_in[1];
    const int*   bias = (const int*)d_in[2];
    const float* is   = (const float*)d_in[3];
    const float* ws   = (const float*)d_in[4];
    const float* os   = (const float*)d_in[5];
    const float* bs   = (const float*)d_in[6];
    int* out = (int*)d_out;

    const int threads = out_size >> 4;         // 2,097,152 (exact)
    const int block   = 256;
    const int grid    = threads / block;       // 8192 (exact)

    qconv1d_kernel<<<grid, block, 0, stream>>>(x, w, bias, is, ws, os, bs, out);
}

// Round 5
// 236.903 us; speedup vs baseline: 1.0463x; 1.0374x over previous
//
#include <hip/hip_runtime.h>

// QCausalConv1D: x[B,D,L] int8 (as int32), weight[D,W=4] int8 (as int32),
// bias[D] int8 (as int32), 4 fp32 scalar scales.
// y[b,d,l] = silu( (sum_{k=0..3} x[b,d,l-3+k]*w[d,k]) * in_s*w_s + bias[d]*b_s )
// out = clip(rint(y/out_s), -128, 127) as int32.
// B=2, D=4096, L=4096 hard-wired (harness shapes are fixed).
//
// R5: per-instruction coalescing fix. R3/R4 gave lanes 32/64-byte strides, so
// each dwordx4 instruction touched 64 cache lines using 16-32B of each (2-4x
// L1/L2 request amplification) -> VMEM-request-rate bound at 2.4 TB/s, VALU
// 20%. Now: one block = one (b,d) row (1024 int4 chunks); each thread does 4
// chunks strided by 256 -> every load/store is 64 lanes x contiguous 16 B.
// Halo chunk (ci-1) loaded the same coalesced way (L1-hot). Weight/bias are
// block-uniform -> scalar loads.

#define DMASK 4095   // D-1

typedef int iv4 __attribute__((ext_vector_type(4)));

__device__ __forceinline__ int silu_requant(float y, float inv_out) {
    // silu(y) = y / (1 + exp(-y)); rintf = round-half-even matches np.round
    float e = __expf(-y);
    float s = y * __builtin_amdgcn_rcpf(1.0f + e);
    float q = rintf(s * inv_out);
    q = fminf(fmaxf(q, -128.0f), 127.0f);
    return (int)q;
}

__global__ __launch_bounds__(256) void qconv1d_kernel(
    const int* __restrict__ x,
    const int* __restrict__ w,
    const int* __restrict__ bias,
    const float* __restrict__ in_s_p,
    const float* __restrict__ w_s_p,
    const float* __restrict__ out_s_p,
    const float* __restrict__ b_s_p,
    int* __restrict__ out)
{
    const int tid  = threadIdx.x;
    const int row  = blockIdx.x;          // b*D + d  (0..8191)
    const int d    = row & DMASK;
    const int rcb  = row << 10;           // row chunk base (1024 chunks/row)

    const iv4* __restrict__ xv = (const iv4*)x;

    // 8 coalesced loads up front: 4 sweeps of cur + 4 of halo (prev chunk).
    // Every instruction: lane stride 16 B -> one 1 KB segment per wave.
    iv4 cur[4], prv[4];
#pragma unroll
    for (int j = 0; j < 4; ++j)
        cur[j] = xv[rcb + (j << 8) + tid];

    {   // j = 0: thread 0 is the row start -> zero halo (and avoids OOB at row 0)
        iv4 p = (iv4){0, 0, 0, 0};
        if (tid != 0) p = xv[rcb + tid - 1];
        prv[0] = p;
    }
#pragma unroll
    for (int j = 1; j < 4; ++j)
        prv[j] = xv[rcb + (j << 8) + tid - 1];

    // Block-uniform weight/bias -> scalar loads.
    iv4 wv = ((const iv4*)w)[d];
    const float w0 = (float)wv.x, w1 = (float)wv.y, w2 = (float)wv.z, w3 = (float)wv.w;
    const float bias_i = (float)bias[d];

    const float in_s  = in_s_p[0];
    const float w_s   = w_s_p[0];
    const float out_s = out_s_p[0];
    const float b_s   = b_s_p[0];

    const float s_xw    = in_s * w_s;
    const float inv_out = 1.0f / out_s;
    const float bf      = bias_i * b_s;

    iv4* __restrict__ ov = (iv4*)out;

#pragma unroll
    for (int j = 0; j < 4; ++j) {
        // s[-3..3] for this chunk; int8 dot exact in fp32
        float sm3 = (float)prv[j].y, sm2 = (float)prv[j].z, sm1 = (float)prv[j].w;
        float s0 = (float)cur[j].x, s1 = (float)cur[j].y,
              s2 = (float)cur[j].z, s3 = (float)cur[j].w;

        float a0 = w0*sm3 + w1*sm2 + w2*sm1 + w3*s0;
        float a1 = w0*sm2 + w1*sm1 + w2*s0  + w3*s1;
        float a2 = w0*sm1 + w1*s0  + w2*s1  + w3*s2;
        float a3 = w0*s0  + w1*s1  + w2*s2  + w3*s3;

        iv4 q;
        q.x = silu_requant(a0 * s_xw + bf, inv_out);
        q.y = silu_requant(a1 * s_xw + bf, inv_out);
        q.z = silu_requant(a2 * s_xw + bf, inv_out);
        q.w = silu_requant(a3 * s_xw + bf, inv_out);

        ov[rcb + (j << 8) + tid] = q;     // coalesced: lane stride 16 B
    }
}

extern "C" void kernel_launch(void* const* d_in, const int* in_sizes, int n_in,
                              void* d_out, int out_size, void* d_ws, size_t ws_size,
                              hipStream_t stream) {
    const int*   x    = (const int*)d_in[0];
    const int*   w    = (const int*)d_in[1];
    const int*   bias = (const int*)d_in[2];
    const float* is   = (const float*)d_in[3];
    const float* ws   = (const float*)d_in[4];
    const float* os   = (const float*)d_in[5];
    const float* bs   = (const float*)d_in[6];
    int* out = (int*)d_out;

    // One block per (b,d) row: 8192 blocks x 256 threads, 4 chunks/thread.
    const int rows  = out_size >> 12;      // 8192 (L=4096 elems/row)
    const int block = 256;

    qconv1d_kernel<<<rows, block, 0, stream>>>(x, w, bias, is, ws, os, bs, out);
}